// Round 9
// baseline (358.144 us; speedup 1.0000x reference)
//
#include <hip/hip_runtime.h>
#include <hip/hip_cooperative_groups.h>

namespace cg = cooperative_groups;

#define N_TOK 2048
#define DMODEL 1024
#define NH 16
#define NKV 4
#define HDIM 64
#define SCALE_LOG2E 0.1803368801111204f  // (1/8) * log2(e)

typedef __attribute__((ext_vector_type(8))) short short8;
typedef __attribute__((ext_vector_type(4))) float f32x4;
typedef unsigned short u16;
typedef unsigned int u32;

__device__ __forceinline__ u16 f2bf(float x) {
    u32 u = __float_as_uint(x);
    u += 0x7FFF + ((u >> 16) & 1);   // round-to-nearest-even
    return (u16)(u >> 16);
}
__device__ __forceinline__ u32 pack2(float a, float b) {
    return (u32)f2bf(a) | ((u32)f2bf(b) << 16);
}
// pack high halves (truncating bf16) of two floats: [bf(a) | bf(b)<<16]
__device__ __forceinline__ u32 pack2t(float a, float b) {
    return __builtin_amdgcn_perm(__float_as_uint(b), __float_as_uint(a), 0x07060302u);
}

struct SmemPrep { float T[64][68]; };                       // 17.4 KB
struct SmemGemm { u16 As[128][40]; u16 Bs[128][40]; };      // 20.5 KB
struct SmemAttn { u16 Ks[2][128][72]; u16 Ps[4][2][16][68]; }; // 54.3 KB

// ---------------------------------------------------------------------------
// ONE cooperative kernel: prep -> sync -> QKV gemm -> sync -> attn -> sync ->
// output gemm. Grid 512 x 256 (2 blocks/CU, exactly co-resident).
// ---------------------------------------------------------------------------
__global__ __launch_bounds__(256, 2) void fused(
    const float* __restrict__ x, const float* __restrict__ fc,
    const float* __restrict__ fs,
    const float* __restrict__ Wq, const float* __restrict__ Wk,
    const float* __restrict__ Wv, const float* __restrict__ Wo,
    u16* __restrict__ Wqt, u16* __restrict__ Wkt, u16* __restrict__ Wvt,
    u16* __restrict__ Wot, u16* __restrict__ xb,
    u16* __restrict__ qb, u16* __restrict__ kb, u16* __restrict__ fv,
    u16* __restrict__ aob, float* __restrict__ out)
{
    __shared__ alignas(16) char smem[sizeof(SmemAttn)];
    const int t = threadIdx.x;
    const int bid = blockIdx.x;
    cg::grid_group grid = cg::this_grid();

    // ======================= PHASE 1: prep =======================
    // jobs: z0 Wq 0..255 | z1 Wk 256..319 | z2 Wv 320..383 | z3 Wo 384..639 |
    //       x-convert 640..895
    {
        float (&T)[64][68] = reinterpret_cast<SmemPrep*>(smem)->T;
        for (int j = bid; j < 896; j += 512) {
            if (j >= 640) {
                size_t base = (size_t)(j - 640) * 8192;
#pragma unroll
                for (int i = 0; i < 8; ++i) {
                    float4 v = *(const float4*)(x + base + i * 1024 + t * 4);
                    uint2 p; p.x = pack2(v.x, v.y); p.y = pack2(v.z, v.w);
                    *(uint2*)(xb + base + i * 1024 + t * 4) = p;
                }
                continue;
            }
            const float* W; u16* Wt; int NC, xb_, yb_;
            if (j < 256)      { W = Wq; Wt = Wqt; NC = 1024; xb_ = j & 15; yb_ = j >> 4; }
            else if (j < 320) { W = Wk; Wt = Wkt; NC = 256;  int q = j - 256; xb_ = q & 3; yb_ = q >> 2; }
            else if (j < 384) { W = Wv; Wt = Wvt; NC = 256;  int q = j - 320; xb_ = q & 3; yb_ = q >> 2; }
            else              { W = Wo; Wt = Wot; NC = 1024; int q = j - 384; xb_ = q & 15; yb_ = q >> 4; }
            const int n0 = xb_ * 64, k0 = yb_ * 64;
            const int row = t >> 2, cs = (t & 3) * 16;
            __syncthreads();   // protect previous job's T reads
#pragma unroll
            for (int i = 0; i < 4; ++i)
                *(float4*)&T[row][cs + i * 4] =
                    *(const float4*)(W + (size_t)(k0 + row) * NC + n0 + cs + i * 4);
            __syncthreads();
            const int nl = t >> 2, ks = (t & 3) * 16;
            u32 pk[8];
#pragma unroll
            for (int i = 0; i < 8; ++i)
                pk[i] = pack2(T[ks + 2 * i][nl], T[ks + 2 * i + 1][nl]);
            u16* dst = Wt + (size_t)(n0 + nl) * DMODEL + k0 + ks;
            uint4 w0; w0.x = pk[0]; w0.y = pk[1]; w0.z = pk[2]; w0.w = pk[3];
            uint4 w1; w1.x = pk[4]; w1.y = pk[5]; w1.z = pk[6]; w1.w = pk[7];
            *(uint4*)(dst) = w0;
            *(uint4*)(dst + 8) = w1;
        }
    }
    grid.sync();

    // ======================= PHASE 2: QKV GEMM =======================
    // 384 jobs: tile 64x128, BK=32. by<8 Q(rope*SCALE) | 8,9 K(rope) | 10,11 FV
    if (bid < 384) {
        SmemGemm* SG = reinterpret_cast<SmemGemm*>(smem);
        const int m0 = (bid & 31) * 64;
        const int by = bid >> 5;
        const u16* Bt; int nl0, ep;
        u16* dbf = nullptr; int dstride = 0; float epsc = 1.f;
        if (by < 8)       { Bt = Wqt; nl0 = by * 128;        dbf = qb; ep = 1; dstride = 1024;
                            epsc = SCALE_LOG2E; }
        else if (by < 10) { Bt = Wkt; nl0 = (by - 8) * 128;  dbf = kb; ep = 1; dstride = 256; }
        else              { Bt = Wvt; nl0 = (by - 10) * 128; ep = 2; }

        const int w = t >> 6, lane = t & 63;
        const int quad = lane >> 4, l15 = lane & 15;
        const int wm = (w >> 1) * 32, wn = (w & 1) * 64;
        const int arow = t >> 2, acol = (t & 3) * 8;
        const int brow = t >> 1, bcol = (t & 1) * 16;

        const u16* Ap = xb + (size_t)(m0 + arow) * DMODEL + acol;
        const u16* Bp = Bt + (size_t)(nl0 + brow) * DMODEL + bcol;

        f32x4 acc[2][4];
#pragma unroll
        for (int i = 0; i < 2; ++i)
#pragma unroll
            for (int j = 0; j < 4; ++j) acc[i][j] = {0.f, 0.f, 0.f, 0.f};

        uint4 ar  = *(const uint4*)(Ap);
        uint4 br0 = *(const uint4*)(Bp);
        uint4 br1 = *(const uint4*)(Bp + 8);

        for (int k0 = 0; k0 < DMODEL; k0 += 32) {
            __syncthreads();
            *(uint4*)&SG->As[arow][acol]     = ar;
            *(uint4*)&SG->Bs[brow][bcol]     = br0;
            *(uint4*)&SG->Bs[brow][bcol + 8] = br1;
            __syncthreads();
            if (k0 + 32 < DMODEL) {
                ar  = *(const uint4*)(Ap + k0 + 32);
                br0 = *(const uint4*)(Bp + k0 + 32);
                br1 = *(const uint4*)(Bp + k0 + 40);
            }
            short8 af[2], bf[4];
#pragma unroll
            for (int i = 0; i < 2; ++i)
                af[i] = *(const short8*)&SG->As[wm + i * 16 + l15][quad * 8];
#pragma unroll
            for (int j = 0; j < 4; ++j)
                bf[j] = *(const short8*)&SG->Bs[wn + j * 16 + l15][quad * 8];
#pragma unroll
            for (int i = 0; i < 2; ++i)
#pragma unroll
                for (int j = 0; j < 4; ++j)
                    acc[i][j] = __builtin_amdgcn_mfma_f32_16x16x32_bf16(af[i], bf[j], acc[i][j], 0, 0, 0);
        }

#pragma unroll
        for (int i = 0; i < 2; ++i)
#pragma unroll
            for (int j = 0; j < 4; ++j) {
                const int cl = nl0 + wn + j * 16 + l15;
#pragma unroll
                for (int r4 = 0; r4 < 4; ++r4) {
                    const int r = m0 + wm + i * 16 + quad * 4 + r4;
                    float own = acc[i][j][r4];
                    if (ep == 1) {
                        float other = __shfl_xor(own, 1, 64);
                        const int p = (cl & 63) >> 1;
                        const float c = fc[r * 32 + p] * epsc, s = fs[r * 32 + p] * epsc;
                        float outv = ((cl & 1) == 0) ? (own * c - other * s)
                                                     : (other * s + own * c);
                        dbf[(size_t)r * dstride + cl] = f2bf(outv);
                    } else {
                        const int g = cl >> 6, d = cl & 63;
                        const int dt = d >> 4, l15v = d & 15;
                        const int kt = r >> 6, klo = r & 63;
                        const int c = klo >> 5, k5 = klo & 31;
                        const int qd = k5 >> 3, jv = k5 & 7;
                        size_t idx = ((((size_t)(g * 32 + kt) * 4 + dt) * 2 + c) * 64
                                      + qd * 16 + l15v) * 8 + jv;
                        fv[idx] = f2bf(own);
                    }
                }
            }
    }
    grid.sync();

    // ======================= PHASE 3: attention =======================
    // 512 jobs exactly: q-tile = bid>>4, head = bid&15. R8 structure.
    {
        SmemAttn* SA = reinterpret_cast<SmemAttn*>(smem);
        const int n0 = (bid >> 4) * 64;
        const int h = bid & 15, kvh = h >> 2;
        const int w = t >> 6, lane = t & 63;
        const int quad = lane >> 4, l15 = lane & 15;
        const int srow = t >> 1, ssel = (t & 1) * 32;

        const u16* qp = qb + (size_t)(n0 + w * 16 + l15) * (NH * HDIM) + h * HDIM + quad * 8;
        const short8 aq0 = *(const short8*)qp;
        const short8 aq1 = *(const short8*)(qp + 32);

        const u16* kbase = kb + (size_t)srow * (NKV * HDIM) + kvh * HDIM + ssel;
        const u16* fvb = fv + ((size_t)kvh * 32 * 4096) + (size_t)lane * 8;

        f32x4 o[4];
#pragma unroll
        for (int i = 0; i < 4; ++i) o[i] = {0.f, 0.f, 0.f, 0.f};
        float l_acc = 0.f;

#pragma unroll
        for (int c = 0; c < 4; ++c)
            *(uint4*)&SA->Ks[0][srow][ssel + c * 8] = *(const uint4*)(kbase + c * 8);
        __syncthreads();

        for (int rd = 0; rd < 16; ++rd) {
            const int cur = rd & 1, nxt = cur ^ 1;
            const int rdn = (rd + 1) & 15;
            uint4 kr[4];
#pragma unroll
            for (int c = 0; c < 4; ++c)
                kr[c] = *(const uint4*)(kbase + (size_t)(rdn * 128) * (NKV * HDIM) + c * 8);

#pragma unroll
            for (int sub = 0; sub < 2; ++sub) {
                const int kt = rd * 2 + sub;
                short8 vf0[4], vf1[4];
#pragma unroll
                for (int dt = 0; dt < 4; ++dt) {
                    vf0[dt] = *(const short8*)(fvb + (size_t)kt * 4096 + (dt * 2 + 0) * 512);
                    vf1[dt] = *(const short8*)(fvb + (size_t)kt * 4096 + (dt * 2 + 1) * 512);
                }
                f32x4 s[4];
#pragma unroll
                for (int nt = 0; nt < 4; ++nt) {
                    short8 kb0 = *(const short8*)&SA->Ks[cur][sub * 64 + nt * 16 + l15][quad * 8];
                    short8 kb1 = *(const short8*)&SA->Ks[cur][sub * 64 + nt * 16 + l15][quad * 8 + 32];
                    f32x4 z = {0.f, 0.f, 0.f, 0.f};
                    z = __builtin_amdgcn_mfma_f32_16x16x32_bf16(kb0, aq0, z, 0, 0, 0);
                    z = __builtin_amdgcn_mfma_f32_16x16x32_bf16(kb1, aq1, z, 0, 0, 0);
                    s[nt] = z;
                }
#pragma unroll
                for (int nt = 0; nt < 4; ++nt) {
                    float p0 = __builtin_amdgcn_exp2f(s[nt][0]);
                    float p1 = __builtin_amdgcn_exp2f(s[nt][1]);
                    float p2 = __builtin_amdgcn_exp2f(s[nt][2]);
                    float p3 = __builtin_amdgcn_exp2f(s[nt][3]);
                    l_acc += (p0 + p1) + (p2 + p3);
                    uint2 pk; pk.x = pack2t(p0, p1); pk.y = pack2t(p2, p3);
                    *(uint2*)&SA->Ps[w][sub][l15][nt * 16 + quad * 4] = pk;
                }
                const short8 ap0 = *(const short8*)&SA->Ps[w][sub][l15][quad * 8];
                const short8 ap1 = *(const short8*)&SA->Ps[w][sub][l15][quad * 8 + 32];
#pragma unroll
                for (int dt = 0; dt < 4; ++dt) {
                    o[dt] = __builtin_amdgcn_mfma_f32_16x16x32_bf16(ap0, vf0[dt], o[dt], 0, 0, 0);
                    o[dt] = __builtin_amdgcn_mfma_f32_16x16x32_bf16(ap1, vf1[dt], o[dt], 0, 0, 0);
                }
            }
#pragma unroll
            for (int c = 0; c < 4; ++c)
                *(uint4*)&SA->Ks[nxt][srow][ssel + c * 8] = kr[c];
            __syncthreads();
        }

        l_acc += __shfl_xor(l_acc, 16, 64);
        l_acc += __shfl_xor(l_acc, 32, 64);
        float linv[4];
#pragma unroll
        for (int r = 0; r < 4; ++r)
            linv[r] = 1.f / __shfl(l_acc, quad * 4 + r, 16);
#pragma unroll
        for (int dt = 0; dt < 4; ++dt)
#pragma unroll
            for (int r = 0; r < 4; ++r) {
                const int qrow = n0 + w * 16 + quad * 4 + r;
                const int col = h * HDIM + dt * 16 + l15;
                aob[(size_t)qrow * (NH * HDIM) + col] = f2bf(o[dt][r] * linv[r]);
            }
    }
    grid.sync();

    // ======================= PHASE 4: output GEMM =======================
    // 256 jobs: tile 64x128, fp32 out.
    if (bid < 256) {
        SmemGemm* SG = reinterpret_cast<SmemGemm*>(smem);
        const int m0 = (bid & 31) * 64;
        const int nl0 = (bid >> 5) * 128;

        const int w = t >> 6, lane = t & 63;
        const int quad = lane >> 4, l15 = lane & 15;
        const int wm = (w >> 1) * 32, wn = (w & 1) * 64;
        const int arow = t >> 2, acol = (t & 3) * 8;
        const int brow = t >> 1, bcol = (t & 1) * 16;

        const u16* Ap = aob + (size_t)(m0 + arow) * DMODEL + acol;
        const u16* Bp = Wot + (size_t)(nl0 + brow) * DMODEL + bcol;

        f32x4 acc[2][4];
#pragma unroll
        for (int i = 0; i < 2; ++i)
#pragma unroll
            for (int j = 0; j < 4; ++j) acc[i][j] = {0.f, 0.f, 0.f, 0.f};

        uint4 ar  = *(const uint4*)(Ap);
        uint4 br0 = *(const uint4*)(Bp);
        uint4 br1 = *(const uint4*)(Bp + 8);

        for (int k0 = 0; k0 < DMODEL; k0 += 32) {
            __syncthreads();
            *(uint4*)&SG->As[arow][acol]     = ar;
            *(uint4*)&SG->Bs[brow][bcol]     = br0;
            *(uint4*)&SG->Bs[brow][bcol + 8] = br1;
            __syncthreads();
            if (k0 + 32 < DMODEL) {
                ar  = *(const uint4*)(Ap + k0 + 32);
                br0 = *(const uint4*)(Bp + k0 + 32);
                br1 = *(const uint4*)(Bp + k0 + 40);
            }
            short8 af[2], bf[4];
#pragma unroll
            for (int i = 0; i < 2; ++i)
                af[i] = *(const short8*)&SG->As[wm + i * 16 + l15][quad * 8];
#pragma unroll
            for (int j = 0; j < 4; ++j)
                bf[j] = *(const short8*)&SG->Bs[wn + j * 16 + l15][quad * 8];
#pragma unroll
            for (int i = 0; i < 2; ++i)
#pragma unroll
                for (int j = 0; j < 4; ++j)
                    acc[i][j] = __builtin_amdgcn_mfma_f32_16x16x32_bf16(af[i], bf[j], acc[i][j], 0, 0, 0);
        }

#pragma unroll
        for (int i = 0; i < 2; ++i)
#pragma unroll
            for (int j = 0; j < 4; ++j) {
                const int cl = nl0 + wn + j * 16 + l15;
#pragma unroll
                for (int r4 = 0; r4 < 4; ++r4) {
                    const int r = m0 + wm + i * 16 + quad * 4 + r4;
                    out[(size_t)r * 1024 + cl] = acc[i][j][r4];
                }
            }
    }
}

// ---------------------------------------------------------------------------
extern "C" void kernel_launch(void* const* d_in, const int* in_sizes, int n_in,
                              void* d_out, int out_size, void* d_ws, size_t ws_size,
                              hipStream_t stream) {
    const float* x  = (const float*)d_in[0];
    const float* fc = (const float*)d_in[1];
    const float* fs = (const float*)d_in[2];
    const float* Wq = (const float*)d_in[3];
    const float* Wk = (const float*)d_in[4];
    const float* Wv = (const float*)d_in[5];
    const float* Wo = (const float*)d_in[6];
    float* out = (float*)d_out;

    u16* ws  = (u16*)d_ws;
    u16* xb  = ws;                         // 2048*1024
    u16* Wqt = xb  + (size_t)2048 * 1024;  // 1024*1024
    u16* Wkt = Wqt + (size_t)1024 * 1024;  // 256*1024
    u16* Wvt = Wkt + (size_t)256 * 1024;   // 256*1024
    u16* Wot = Wvt + (size_t)256 * 1024;   // 1024*1024
    u16* qb  = Wot + (size_t)1024 * 1024;  // 2048*1024
    u16* kb  = qb  + (size_t)2048 * 1024;  // 2048*256
    u16* fv  = kb  + (size_t)2048 * 256;   // 256*2048 (fragment-packed V)
    u16* aob = fv  + (size_t)256 * 2048;   // 2048*1024

    void* args[] = {
        (void*)&x, (void*)&fc, (void*)&fs,
        (void*)&Wq, (void*)&Wk, (void*)&Wv, (void*)&Wo,
        (void*)&Wqt, (void*)&Wkt, (void*)&Wvt, (void*)&Wot, (void*)&xb,
        (void*)&qb, (void*)&kb, (void*)&fv, (void*)&aob, (void*)&out
    };
    hipLaunchCooperativeKernel((const void*)fused, dim3(512), dim3(256),
                               args, 0, stream);
}